// Round 12
// baseline (149.213 us; speedup 1.0000x reference)
//
#include <hip/hip_runtime.h>
#include <hip/hip_bf16.h>
#include <math.h>

#define T_DIM 2048
#define B_DIM 2
#define E_DIM 1024
#define H_DIM 16
#define HD_DIM 64
#define M_DIM (T_DIM * B_DIM)   // 4096 rows (t*B+b)
#define BH_DIM (B_DIM * H_DIM)  // 32 head-batches

using bf16x8 = __attribute__((ext_vector_type(8))) __bf16;
using u16x8  = __attribute__((ext_vector_type(8))) unsigned short;
using f32x4  = __attribute__((ext_vector_type(4))) float;

static __device__ __forceinline__ unsigned short f2bf(float f) {
  unsigned u = __builtin_bit_cast(unsigned, f);
  u += 0x7fff + ((u >> 16) & 1);   // RNE
  return (unsigned short)(u >> 16);
}
static __device__ __forceinline__ float bf2f(unsigned short x) {
  return __builtin_bit_cast(float, (unsigned)x << 16);
}

__device__ __forceinline__ void gload_lds16(const void* g, void* l) {
  __builtin_amdgcn_global_load_lds(
      (const __attribute__((address_space(1))) unsigned int*)g,
      (__attribute__((address_space(3))) unsigned int*)l, 16, 0, 0);
}

// ---------------- fp32 -> bf16 cast (both weights, one launch) -------------
__global__ __launch_bounds__(256) void cast2_kernel(
    const float* __restrict__ in1, unsigned short* __restrict__ out1, int n1,
    const float* __restrict__ in2, unsigned short* __restrict__ out2, int n2) {
  int i = blockIdx.x * 256 + threadIdx.x;
  const float* in; unsigned short* out; int idx;
  if (i < n1) { in = in1; out = out1; idx = i; }
  else if (i < n1 + n2) { in = in2; out = out2; idx = i - n1; }
  else return;
  float4 v = ((const float4*)in)[idx];
  ushort4 o;
  o.x = f2bf(v.x); o.y = f2bf(v.y); o.z = f2bf(v.z); o.w = f2bf(v.w);
  ((ushort4*)out)[idx] = o;
}

// ---------------- LayerNorm (row = one block) ----------------
__global__ __launch_bounds__(256) void ln_kernel(
    const float* __restrict__ q, const float* __restrict__ gamma,
    const float* __restrict__ beta, unsigned short* __restrict__ out) {
  int row = blockIdx.x;
  int tid = threadIdx.x;
  const float4* qr = (const float4*)(q + (size_t)row * E_DIM);
  float4 x = qr[tid];
  float s  = x.x + x.y + x.z + x.w;
  float ss = x.x * x.x + x.y * x.y + x.z * x.z + x.w * x.w;
#pragma unroll
  for (int off = 32; off >= 1; off >>= 1) {
    s  += __shfl_xor(s, off, 64);
    ss += __shfl_xor(ss, off, 64);
  }
  __shared__ float red[8];
  int wid = tid >> 6, lane = tid & 63;
  if (lane == 0) { red[wid] = s; red[4 + wid] = ss; }
  __syncthreads();
  s  = red[0] + red[1] + red[2] + red[3];
  ss = red[4] + red[5] + red[6] + red[7];
  float mean = s * (1.0f / E_DIM);
  float var  = ss * (1.0f / E_DIM) - mean * mean;
  float rstd = rsqrtf(var + 1e-5f);
  float4 g4 = ((const float4*)gamma)[tid];
  float4 b4 = ((const float4*)beta)[tid];
  ushort4 o;
  o.x = f2bf((x.x - mean) * rstd * g4.x + b4.x);
  o.y = f2bf((x.y - mean) * rstd * g4.y + b4.y);
  o.z = f2bf((x.z - mean) * rstd * g4.z + b4.z);
  o.w = f2bf((x.w - mean) * rstd * g4.w + b4.w);
  ((ushort4*)(out + (size_t)row * E_DIM))[tid] = o;
}

// ---------------- GEMM0: qkv = ln @ Win^T ---------------------------------
// q -> [bh][t][64]; k -> [bh][t][64]; v -> vt [bh][d][perm-t] (transpose +
// key-permutation fused; p(trow) is the inverse of attn's tl(p) mapping)
__global__ __launch_bounds__(256) void gemm0_kernel(
    const unsigned short* __restrict__ A, const unsigned short* __restrict__ Bw,
    unsigned short* __restrict__ out_q, unsigned short* __restrict__ out_k,
    unsigned short* __restrict__ out_vt) {
  __shared__ alignas(16) unsigned short lA[128 * 32];
  __shared__ alignas(16) unsigned short lB[128 * 32];
  int tid = threadIdx.x;
  int wid = tid >> 6, lane = tid & 63;
  int wm = wid >> 1, wn = wid & 1;
  int g = lane >> 4, lr = lane & 15;
  int m0 = blockIdx.y * 128, n0 = blockIdx.x * 128;
  f32x4 acc[4][4] = {};

  for (int k0 = 0; k0 < E_DIM; k0 += 32) {
#pragma unroll
    for (int c = 0; c < 2; ++c) {
      int f16 = c * 256 + tid;
      int row = f16 >> 2, col8 = (f16 & 3) << 3;
      gload_lds16(A  + (size_t)(m0 + row) * E_DIM + k0 + col8,
                  lA + (size_t)(c * 256 + wid * 64) * 8);
      gload_lds16(Bw + (size_t)(n0 + row) * E_DIM + k0 + col8,
                  lB + (size_t)(c * 256 + wid * 64) * 8);
    }
    __syncthreads();
    bf16x8 af[4], bfr[4];
#pragma unroll
    for (int r = 0; r < 4; ++r) {
      af[r]  = *(const bf16x8*)(lA + (wm * 64 + r * 16 + lr) * 32 + g * 8);
      bfr[r] = *(const bf16x8*)(lB + (wn * 64 + r * 16 + lr) * 32 + g * 8);
    }
#pragma unroll
    for (int mr = 0; mr < 4; ++mr)
#pragma unroll
      for (int nr = 0; nr < 4; ++nr)
        acc[mr][nr] = __builtin_amdgcn_mfma_f32_16x16x32_bf16(
            af[mr], bfr[nr], acc[mr][nr], 0, 0, 0);
    __syncthreads();
  }

#pragma unroll
  for (int mr = 0; mr < 4; ++mr) {
#pragma unroll
    for (int nr = 0; nr < 4; ++nr) {
#pragma unroll
      for (int r = 0; r < 4; ++r) {
        int grow = m0 + wm * 64 + mr * 16 + g * 4 + r;
        int gcol = n0 + wn * 64 + nr * 16 + lr;
        int which = gcol >> 10, rem = gcol & 1023;
        int h = rem >> 6, d = rem & 63;
        int t = grow >> 1, b = grow & 1;
        size_t bh = (size_t)(b * H_DIM + h);
        unsigned short val = f2bf(acc[mr][nr][r]);
        if (which == 0) {
          out_q[(bh * T_DIM + t) * HD_DIM + d] = val;
        } else if (which == 1) {
          out_k[(bh * T_DIM + t) * HD_DIM + d] = val;
        } else {
          int tile = t >> 6, trow = t & 63;
          int cf = trow >> 4, rr = trow & 15;
          int ks2 = cf >> 1, jh = cf & 1, g2 = rr >> 2, jl = rr & 3;
          int p = ks2 * 32 + g2 * 8 + jh * 4 + jl;
          out_vt[bh * (HD_DIM * T_DIM) + (size_t)d * T_DIM + tile * 64 + p] = val;
        }
      }
    }
  }
}

// ---------------- GEMM1: out = resid + ctx @ Wout^T (128x64 tile) --------
__global__ __launch_bounds__(256) void gemm1_kernel(
    const unsigned short* __restrict__ A, const unsigned short* __restrict__ Bw,
    const float* __restrict__ resid, float* __restrict__ out) {
  __shared__ alignas(16) unsigned short lA[128 * 32];
  __shared__ alignas(16) unsigned short lB[64 * 32];
  int tid = threadIdx.x;
  int wid = tid >> 6, lane = tid & 63;
  int g = lane >> 4, lr = lane & 15;
  int m0 = blockIdx.y * 128, n0 = blockIdx.x * 64;
  f32x4 acc[2][4] = {};

  for (int k0 = 0; k0 < E_DIM; k0 += 32) {
#pragma unroll
    for (int c = 0; c < 2; ++c) {
      int f16 = c * 256 + tid;
      int row = f16 >> 2, col8 = (f16 & 3) << 3;
      gload_lds16(A + (size_t)(m0 + row) * E_DIM + k0 + col8,
                  lA + (size_t)(c * 256 + wid * 64) * 8);
    }
    {
      int row = tid >> 2, col8 = (tid & 3) << 3;
      gload_lds16(Bw + (size_t)(n0 + row) * E_DIM + k0 + col8,
                  lB + (size_t)(wid * 64) * 8);
    }
    __syncthreads();
    bf16x8 af[2], bfr[4];
#pragma unroll
    for (int r = 0; r < 2; ++r)
      af[r] = *(const bf16x8*)(lA + (wid * 32 + r * 16 + lr) * 32 + g * 8);
#pragma unroll
    for (int r = 0; r < 4; ++r)
      bfr[r] = *(const bf16x8*)(lB + (r * 16 + lr) * 32 + g * 8);
#pragma unroll
    for (int mr = 0; mr < 2; ++mr)
#pragma unroll
      for (int nr = 0; nr < 4; ++nr)
        acc[mr][nr] = __builtin_amdgcn_mfma_f32_16x16x32_bf16(
            af[mr], bfr[nr], acc[mr][nr], 0, 0, 0);
    __syncthreads();
  }

#pragma unroll
  for (int mr = 0; mr < 2; ++mr) {
#pragma unroll
    for (int nr = 0; nr < 4; ++nr) {
#pragma unroll
      for (int r = 0; r < 4; ++r) {
        int grow = m0 + wid * 32 + mr * 16 + g * 4 + r;
        int gcol = n0 + nr * 16 + lr;
        size_t idx = (size_t)grow * E_DIM + gcol;
        out[idx] = resid[idx] + acc[mr][nr][r];
      }
    }
  }
}

// ---------------- Flash attention v7: KV-split x2 + r11 pipeline ----------
// Grid 1024 = 8 xcd x 4 bh x 16 qt x 2 s -> 4096 waves (4/SIMD). 2-buffer
// LDS (32 KB -> 4 blocks/CU). Per tile: barrier; stage(t+1 -> buf^1);
// vmcnt(4); barrier; compute(buf). Swapped QK^T -> register P (r11 verbatim).
// Fixed-max softmax: disjoint-KV partials exactly additive; writes
// unnormalized O^T (bf16) + rowsum S (fp32).
__global__ __launch_bounds__(256) void attn_kernel(
    const unsigned short* __restrict__ qb, const unsigned short* __restrict__ kb,
    const unsigned short* __restrict__ vt, unsigned short* __restrict__ pO,
    float* __restrict__ pS) {
  __shared__ alignas(16) unsigned short lK[2][64 * 64];
  __shared__ alignas(16) unsigned short lV[2][64 * 64];
  int tid = threadIdx.x;
  int wid = tid >> 6, lane = tid & 63;
  int g = lane >> 4, lr = lane & 15;
  int f = blockIdx.x;                  // 0..1023
  int xcd = f & 7, rest = f >> 3;
  int bh = xcd + 8 * (rest & 3);       // 4 bh per XCD -> K/V L2-resident
  int qt = (rest >> 2) & 15;           // 128-row q-tile
  int s  = (rest >> 6) & 1;            // KV half
  const size_t koff = (size_t)bh * T_DIM * HD_DIM;   // q,k layout [bh][t][64]
  const size_t voff = (size_t)bh * HD_DIM * T_DIM;   // v^T layout [bh][64][T]

  int srow = tid >> 3;
  int gch  = (tid & 7) ^ (srow & 7);
  const unsigned short* ks0 = kb + koff +
      ((size_t)(s * 1024) + srow) * HD_DIM + gch * 8;
  const unsigned short* vs0 = vt + voff +
      (size_t)srow * T_DIM + s * 1024 + gch * 8;

#define STAGE_TILE(buf, kofs, vofs)                                            \
  do {                                                                         \
    gload_lds16(ks0 + (kofs),                 lK[buf] + wid * 512);            \
    gload_lds16(ks0 + (kofs) + 32 * HD_DIM,   lK[buf] + 2048 + wid * 512);     \
    gload_lds16(vs0 + (vofs),                 lV[buf] + wid * 512);            \
    gload_lds16(vs0 + (vofs) + (size_t)32 * T_DIM, lV[buf] + 2048 + wid * 512);\
  } while (0)

  // Q fragments (32 q per wave, q = lr within each qa half), QS folded in
  bf16x8 qf[2][2];
  {
    const float QS = 0.125f * 1.44269504f;
#pragma unroll
    for (int qa = 0; qa < 2; ++qa) {
      int qrow = qt * 128 + wid * 32 + qa * 16 + lr;
#pragma unroll
      for (int ks = 0; ks < 2; ++ks) {
        bf16x8 raw = *(const bf16x8*)(qb + koff + (size_t)qrow * HD_DIM + ks * 32 + g * 8);
#pragma unroll
        for (int j = 0; j < 8; ++j) qf[qa][ks][j] = (__bf16)((float)raw[j] * QS);
      }
    }
  }

  bf16x8 onesf;
#pragma unroll
  for (int j = 0; j < 8; ++j) onesf[j] = (__bf16)1.0f;

  f32x4 accO[2][4] = {};   // accO[qa][df]: O^T[d=df*16+g*4+r][q=lr] partial
  f32x4 accS[2] = {};

  STAGE_TILE(0, 0, 0);     // prologue: tile 0 of this half

#define PROCESS(BUF, TT, LAST)                                                 \
  do {                                                                         \
    __builtin_amdgcn_s_barrier();      /* all waves done reading buf^1 */      \
    if (!(LAST)) {                                                             \
      size_t s1 = (size_t)((TT) + 1) * 64;                                     \
      STAGE_TILE((BUF) ^ 1, s1 * HD_DIM, s1);                                  \
      asm volatile("s_waitcnt vmcnt(4)" ::: "memory");                         \
    } else {                                                                   \
      asm volatile("s_waitcnt vmcnt(0)" ::: "memory");                         \
    }                                                                          \
    __builtin_amdgcn_s_barrier();      /* cross-wave: tile TT staged */        \
    __builtin_amdgcn_sched_barrier(0);                                         \
    const unsigned short* Kc = lK[BUF];                                        \
    const unsigned short* Vc = lV[BUF];                                        \
    f32x4 s4[2][4];                                                            \
    __builtin_amdgcn_s_setprio(1);                                             \
    _Pragma("unroll")                                                          \
    for (int cf = 0; cf < 4; ++cf) {                                           \
      int row = cf * 16 + lr;                                                  \
      int sw = (row & 7) << 3;                                                 \
      bf16x8 k0 = *(const bf16x8*)(Kc + row * 64 + ((g * 8) ^ sw));            \
      bf16x8 k1 = *(const bf16x8*)(Kc + row * 64 + ((32 + g * 8) ^ sw));       \
      _Pragma("unroll")                                                        \
      for (int qa = 0; qa < 2; ++qa) {                                         \
        f32x4 s = {-8.0f, -8.0f, -8.0f, -8.0f};                                \
        s = __builtin_amdgcn_mfma_f32_16x16x32_bf16(k0, qf[qa][0], s, 0, 0, 0);\
        s = __builtin_amdgcn_mfma_f32_16x16x32_bf16(k1, qf[qa][1], s, 0, 0, 0);\
        s4[qa][cf] = s;                                                        \
      }                                                                        \
    }                                                                          \
    __builtin_amdgcn_s_setprio(0);                                             \
    bf16x8 pf[2][2];                                                           \
    _Pragma("unroll")                                                          \
    for (int qa = 0; qa < 2; ++qa)                                             \
      _Pragma("unroll")                                                        \
      for (int j = 0; j < 8; ++j) {                                            \
        pf[qa][0][j] = (__bf16)__builtin_amdgcn_exp2f(s4[qa][(j >> 2)][j & 3]);\
        pf[qa][1][j] = (__bf16)__builtin_amdgcn_exp2f(s4[qa][2 + (j >> 2)][j & 3]);\
      }                                                                        \
    __builtin_amdgcn_s_setprio(1);                                             \
    _Pragma("unroll")                                                          \
    for (int ks = 0; ks < 2; ++ks) {                                           \
      _Pragma("unroll")                                                        \
      for (int qa = 0; qa < 2; ++qa)                                           \
        accS[qa] = __builtin_amdgcn_mfma_f32_16x16x32_bf16(onesf, pf[qa][ks], accS[qa], 0, 0, 0); \
      _Pragma("unroll")                                                        \
      for (int df = 0; df < 4; ++df) {                                         \
        int row = df * 16 + lr;                                                \
        int sw = (row & 7) << 3;                                               \
        bf16x8 vf = *(const bf16x8*)(Vc + row * 64 + ((ks * 32 + g * 8) ^ sw));\
        _Pragma("unroll")                                                      \
        for (int qa = 0; qa < 2; ++qa)                                         \
          accO[qa][df] = __builtin_amdgcn_mfma_f32_16x16x32_bf16(vf, pf[qa][ks], accO[qa][df], 0, 0, 0); \
      }                                                                        \
    }                                                                          \
    __builtin_amdgcn_s_setprio(0);                                             \
  } while (0)

  for (int t2 = 0; t2 < 16; t2 += 2) {
    PROCESS(0, t2, false);
    PROCESS(1, t2 + 1, t2 + 1 == 15);
  }
#undef PROCESS
#undef STAGE_TILE

  // store unnormalized partials: pO[(s*32+bh)*16+qt][d(64)][q(128)] bf16
  unsigned short* pOb = pO + (size_t)((s * 32 + bh) * 16 + qt) * (64 * 128);
#pragma unroll
  for (int qa = 0; qa < 2; ++qa)
#pragma unroll
    for (int df = 0; df < 4; ++df)
#pragma unroll
      for (int r = 0; r < 4; ++r)
        pOb[(df * 16 + g * 4 + r) * 128 + wid * 32 + qa * 16 + lr] =
            f2bf(accO[qa][df][r]);
  if (g == 0) {
    float* pSb = pS + (size_t)((s * 32 + bh) * 16 + qt) * 128;
#pragma unroll
    for (int qa = 0; qa < 2; ++qa)
      pSb[wid * 32 + qa * 16 + lr] = accS[qa][0];
  }
}

// ---------------- combine partials: ctx = (O0+O1)/(S0+S1), transpose ------
__global__ __launch_bounds__(256) void reduce_kernel(
    const unsigned short* __restrict__ pO, const float* __restrict__ pS,
    unsigned short* __restrict__ ctx) {
  __shared__ float lo[64][65];
  __shared__ float ls[64];
  int tid = threadIdx.x;
  int bq = blockIdx.x;               // 0..1023
  int bh = bq & 31, qt2 = bq >> 5;   // qt2: 64-row group 0..31
  int b = bh >> 4, h = bh & 15;
  int qt = qt2 >> 1, half = qt2 & 1;
  size_t base0 = (size_t)((0 * 32 + bh) * 16 + qt) * 8192 + half * 64;
  size_t base1 = (size_t)((1 * 32 + bh) * 16 + qt) * 8192 + half * 64;
  int d = tid >> 2, c = (tid & 3) * 16;
  u16x8 a0 = *(const u16x8*)(pO + base0 + d * 128 + c);
  u16x8 a1 = *(const u16x8*)(pO + base0 + d * 128 + c + 8);
  u16x8 b0 = *(const u16x8*)(pO + base1 + d * 128 + c);
  u16x8 b1 = *(const u16x8*)(pO + base1 + d * 128 + c + 8);
#pragma unroll
  for (int j = 0; j < 8; ++j) {
    lo[d][c + j]     = bf2f(a0[j]) + bf2f(b0[j]);
    lo[d][c + 8 + j] = bf2f(a1[j]) + bf2f(b1[j]);
  }
  if (tid < 64)
    ls[tid] = pS[(size_t)((0 * 32 + bh) * 16 + qt) * 128 + half * 64 + tid] +
              pS[(size_t)((1 * 32 + bh) * 16 + qt) * 128 + half * 64 + tid];
  __syncthreads();
  int q = tid >> 2, dc = tid & 3;
  float inv = 1.0f / ls[q];
  u16x8 o0, o1;
#pragma unroll
  for (int k = 0; k < 8; ++k) {
    o0[k] = f2bf(lo[dc * 16 + k][q] * inv);
    o1[k] = f2bf(lo[dc * 16 + 8 + k][q] * inv);
  }
  size_t row = ((size_t)(qt2 * 64 + q) * B_DIM + b) * E_DIM + h * HD_DIM + dc * 16;
  *(u16x8*)(ctx + row)     = o0;
  *(u16x8*)(ctx + row + 8) = o1;
}

// ---------------- launcher ----------------
extern "C" void kernel_launch(void* const* d_in, const int* in_sizes, int n_in,
                              void* d_out, int out_size, void* d_ws, size_t ws_size,
                              hipStream_t stream) {
  const float* query = (const float*)d_in[0];
  const float* gamma = (const float*)d_in[1];
  const float* beta  = (const float*)d_in[2];
  const float* w_in  = (const float*)d_in[3];
  const float* w_out = (const float*)d_in[4];
  float* out = (float*)d_out;

  unsigned short* ws    = (unsigned short*)d_ws;
  unsigned short* ln    = ws;                                  // 8 MB
  unsigned short* winb  = ln    + (size_t)M_DIM * E_DIM;       // 6 MB
  unsigned short* woutb = winb  + (size_t)3 * E_DIM * E_DIM;   // 2 MB
  unsigned short* qbuf  = woutb + (size_t)E_DIM * E_DIM;       // 8 MB
  unsigned short* kbuf  = qbuf  + (size_t)BH_DIM * T_DIM * HD_DIM; // 8 MB
  unsigned short* vtb   = kbuf  + (size_t)BH_DIM * T_DIM * HD_DIM; // 8 MB
  unsigned short* pO    = vtb   + (size_t)BH_DIM * HD_DIM * T_DIM; // 16 MB
  float*          pS    = (float*)(pO + (size_t)2 * BH_DIM * 16 * 64 * 128); // 0.5 MB
  unsigned short* ctx   = ln;   // reuse: ln consumed by gemm0 before reduce writes

  cast2_kernel<<<dim3(4096), dim3(256), 0, stream>>>(
      w_in, winb, 3 * E_DIM * E_DIM / 4, w_out, woutb, E_DIM * E_DIM / 4);
  ln_kernel<<<dim3(M_DIM), dim3(256), 0, stream>>>(query, gamma, beta, ln);
  gemm0_kernel<<<dim3(3 * E_DIM / 128, M_DIM / 128), dim3(256), 0, stream>>>(
      ln, winb, qbuf, kbuf, vtb);
  attn_kernel<<<dim3(1024), dim3(256), 0, stream>>>(qbuf, kbuf, vtb, pO, pS);
  reduce_kernel<<<dim3(1024), dim3(256), 0, stream>>>(pO, pS, ctx);
  gemm1_kernel<<<dim3(E_DIM / 64, M_DIM / 128), dim3(256), 0, stream>>>(
      ctx, woutb, query, out);
}

// Round 13
// 130.138 us; speedup vs baseline: 1.1466x; 1.1466x over previous
//
#include <hip/hip_runtime.h>
#include <hip/hip_bf16.h>
#include <math.h>

#define T_DIM 2048
#define B_DIM 2
#define E_DIM 1024
#define H_DIM 16
#define HD_DIM 64
#define M_DIM (T_DIM * B_DIM)   // 4096 rows (t*B+b)
#define BH_DIM (B_DIM * H_DIM)  // 32 head-batches

using bf16x8 = __attribute__((ext_vector_type(8))) __bf16;
using u16x8  = __attribute__((ext_vector_type(8))) unsigned short;
using f32x4  = __attribute__((ext_vector_type(4))) float;

static __device__ __forceinline__ unsigned short f2bf(float f) {
  unsigned u = __builtin_bit_cast(unsigned, f);
  u += 0x7fff + ((u >> 16) & 1);   // RNE
  return (unsigned short)(u >> 16);
}
static __device__ __forceinline__ float bf2f(unsigned short x) {
  return __builtin_bit_cast(float, (unsigned)x << 16);
}

__device__ __forceinline__ void gload_lds16(const void* g, void* l) {
  __builtin_amdgcn_global_load_lds(
      (const __attribute__((address_space(1))) unsigned int*)g,
      (__attribute__((address_space(3))) unsigned int*)l, 16, 0, 0);
}

// ---------------- prep: LN rows (blocks 0..4095) + weight casts (4096..8191)
__global__ __launch_bounds__(256) void prep_kernel(
    const float* __restrict__ q, const float* __restrict__ gamma,
    const float* __restrict__ beta, unsigned short* __restrict__ ln_out,
    const float* __restrict__ w1, unsigned short* __restrict__ o1, int n1,
    const float* __restrict__ w2, unsigned short* __restrict__ o2, int n2) {
  int blk = blockIdx.x;
  int tid = threadIdx.x;
  if (blk >= M_DIM) {
    int i = (blk - M_DIM) * 256 + tid;
    const float* in; unsigned short* out; int idx;
    if (i < n1) { in = w1; out = o1; idx = i; }
    else if (i < n1 + n2) { in = w2; out = o2; idx = i - n1; }
    else return;
    float4 v = ((const float4*)in)[idx];
    ushort4 o;
    o.x = f2bf(v.x); o.y = f2bf(v.y); o.z = f2bf(v.z); o.w = f2bf(v.w);
    ((ushort4*)out)[idx] = o;
    return;
  }
  int row = blk;
  const float4* qr = (const float4*)(q + (size_t)row * E_DIM);
  float4 x = qr[tid];
  float s  = x.x + x.y + x.z + x.w;
  float ss = x.x * x.x + x.y * x.y + x.z * x.z + x.w * x.w;
#pragma unroll
  for (int off = 32; off >= 1; off >>= 1) {
    s  += __shfl_xor(s, off, 64);
    ss += __shfl_xor(ss, off, 64);
  }
  __shared__ float red[8];
  int wid = tid >> 6, lane = tid & 63;
  if (lane == 0) { red[wid] = s; red[4 + wid] = ss; }
  __syncthreads();
  s  = red[0] + red[1] + red[2] + red[3];
  ss = red[4] + red[5] + red[6] + red[7];
  float mean = s * (1.0f / E_DIM);
  float var  = ss * (1.0f / E_DIM) - mean * mean;
  float rstd = rsqrtf(var + 1e-5f);
  float4 g4 = ((const float4*)gamma)[tid];
  float4 b4 = ((const float4*)beta)[tid];
  ushort4 o;
  o.x = f2bf((x.x - mean) * rstd * g4.x + b4.x);
  o.y = f2bf((x.y - mean) * rstd * g4.y + b4.y);
  o.z = f2bf((x.z - mean) * rstd * g4.z + b4.z);
  o.w = f2bf((x.w - mean) * rstd * g4.w + b4.w);
  ((ushort4*)(ln_out + (size_t)row * E_DIM))[tid] = o;
}

// ---------------- GEMM0: qkv = ln @ Win^T, scatter to [3][bh][t][64] ------
// (r11 version: all three outputs coalesced 16-lane u16 runs)
__global__ __launch_bounds__(256) void gemm0_kernel(
    const unsigned short* __restrict__ A, const unsigned short* __restrict__ Bw,
    unsigned short* __restrict__ out_qkv) {
  __shared__ alignas(16) unsigned short lA[128 * 32];
  __shared__ alignas(16) unsigned short lB[128 * 32];
  int tid = threadIdx.x;
  int wid = tid >> 6, lane = tid & 63;
  int wm = wid >> 1, wn = wid & 1;
  int g = lane >> 4, lr = lane & 15;
  int m0 = blockIdx.y * 128, n0 = blockIdx.x * 128;
  f32x4 acc[4][4] = {};

  for (int k0 = 0; k0 < E_DIM; k0 += 32) {
#pragma unroll
    for (int c = 0; c < 2; ++c) {
      int f16 = c * 256 + tid;
      int row = f16 >> 2, col8 = (f16 & 3) << 3;
      gload_lds16(A  + (size_t)(m0 + row) * E_DIM + k0 + col8,
                  lA + (size_t)(c * 256 + wid * 64) * 8);
      gload_lds16(Bw + (size_t)(n0 + row) * E_DIM + k0 + col8,
                  lB + (size_t)(c * 256 + wid * 64) * 8);
    }
    __syncthreads();
    bf16x8 af[4], bfr[4];
#pragma unroll
    for (int r = 0; r < 4; ++r) {
      af[r]  = *(const bf16x8*)(lA + (wm * 64 + r * 16 + lr) * 32 + g * 8);
      bfr[r] = *(const bf16x8*)(lB + (wn * 64 + r * 16 + lr) * 32 + g * 8);
    }
#pragma unroll
    for (int mr = 0; mr < 4; ++mr)
#pragma unroll
      for (int nr = 0; nr < 4; ++nr)
        acc[mr][nr] = __builtin_amdgcn_mfma_f32_16x16x32_bf16(
            af[mr], bfr[nr], acc[mr][nr], 0, 0, 0);
    __syncthreads();
  }

#pragma unroll
  for (int mr = 0; mr < 4; ++mr) {
#pragma unroll
    for (int nr = 0; nr < 4; ++nr) {
#pragma unroll
      for (int r = 0; r < 4; ++r) {
        int grow = m0 + wm * 64 + mr * 16 + g * 4 + r;
        int gcol = n0 + wn * 64 + nr * 16 + lr;
        int which = gcol >> 10, rem = gcol & 1023;
        int h = rem >> 6, d = rem & 63;
        int t = grow >> 1, b = grow & 1;
        out_qkv[(size_t)which * (BH_DIM * T_DIM * HD_DIM) +
                ((size_t)(b * H_DIM + h) * T_DIM + t) * HD_DIM + d] =
            f2bf(acc[mr][nr][r]);
      }
    }
  }
}

// ---------------- GEMM1: out = resid + ctx @ Wout^T (128x64 tile) --------
__global__ __launch_bounds__(256) void gemm1_kernel(
    const unsigned short* __restrict__ A, const unsigned short* __restrict__ Bw,
    const float* __restrict__ resid, float* __restrict__ out) {
  __shared__ alignas(16) unsigned short lA[128 * 32];
  __shared__ alignas(16) unsigned short lB[64 * 32];
  int tid = threadIdx.x;
  int wid = tid >> 6, lane = tid & 63;
  int g = lane >> 4, lr = lane & 15;
  int m0 = blockIdx.y * 128, n0 = blockIdx.x * 64;
  f32x4 acc[2][4] = {};

  for (int k0 = 0; k0 < E_DIM; k0 += 32) {
#pragma unroll
    for (int c = 0; c < 2; ++c) {
      int f16 = c * 256 + tid;
      int row = f16 >> 2, col8 = (f16 & 3) << 3;
      gload_lds16(A + (size_t)(m0 + row) * E_DIM + k0 + col8,
                  lA + (size_t)(c * 256 + wid * 64) * 8);
    }
    {
      int row = tid >> 2, col8 = (tid & 3) << 3;
      gload_lds16(Bw + (size_t)(n0 + row) * E_DIM + k0 + col8,
                  lB + (size_t)(wid * 64) * 8);
    }
    __syncthreads();
    bf16x8 af[2], bfr[4];
#pragma unroll
    for (int r = 0; r < 2; ++r)
      af[r] = *(const bf16x8*)(lA + (wid * 32 + r * 16 + lr) * 32 + g * 8);
#pragma unroll
    for (int r = 0; r < 4; ++r)
      bfr[r] = *(const bf16x8*)(lB + (r * 16 + lr) * 32 + g * 8);
#pragma unroll
    for (int mr = 0; mr < 2; ++mr)
#pragma unroll
      for (int nr = 0; nr < 4; ++nr)
        acc[mr][nr] = __builtin_amdgcn_mfma_f32_16x16x32_bf16(
            af[mr], bfr[nr], acc[mr][nr], 0, 0, 0);
    __syncthreads();
  }

#pragma unroll
  for (int mr = 0; mr < 2; ++mr) {
#pragma unroll
    for (int nr = 0; nr < 4; ++nr) {
#pragma unroll
      for (int r = 0; r < 4; ++r) {
        int grow = m0 + wid * 32 + mr * 16 + g * 4 + r;
        int gcol = n0 + nr * 16 + lr;
        size_t idx = (size_t)grow * E_DIM + gcol;
        out[idx] = resid[idx] + acc[mr][nr][r];
      }
    }
  }
}

// ---------------- V transpose: [bh][t][d] -> [bh][d][perm(t)] -------------
// (r11 version) column p holds logical key tl(p) = (ks*2+(j>>2))*16+g*4+(j&3),
// ks=p>>5, g=(p>>3)&3, j=p&7 — matches attn's register-P layout.
__global__ __launch_bounds__(256) void transpose_v_kernel(
    const unsigned short* __restrict__ vb, unsigned short* __restrict__ vt) {
  __shared__ alignas(16) unsigned short tl[64 * 72];
  int tid = threadIdx.x;
  int bh = blockIdx.y, t0 = blockIdx.x * 64;
  const unsigned short* src = vb + ((size_t)bh * T_DIM + t0) * HD_DIM;
#pragma unroll
  for (int e = 0; e < 2; ++e) {
    int i8 = e * 256 + tid;
    int r = i8 >> 3;
    int c = (i8 & 7) * 8;
    int hsh = (r ^ (r >> 3)) & 7;
    bf16x8 v = *(const bf16x8*)(src + (size_t)r * HD_DIM + c);
    *(bf16x8*)(tl + r * 72 + (c ^ (hsh << 3))) = v;
  }
  __syncthreads();
  unsigned short* dst = vt + (size_t)bh * HD_DIM * T_DIM + t0;
#pragma unroll
  for (int e = 0; e < 2; ++e) {
    int i8 = e * 256 + tid;
    int d = i8 >> 3;
    int tc = (i8 & 7) * 8;
    u16x8 o;
#pragma unroll
    for (int j = 0; j < 8; ++j) {
      int p = tc + j;
      int ks = p >> 5, gg = (p >> 3) & 3, jl = p & 7;
      int r = (ks * 2 + (jl >> 2)) * 16 + gg * 4 + (jl & 3);
      int hsh = (r ^ (r >> 3)) & 7;
      o[j] = tl[r * 72 + (d ^ (hsh << 3))];
    }
    *(u16x8*)(dst + (size_t)d * T_DIM + tc) = o;
  }
}

// ---------------- Flash attention (r12): KV-split x2 + LDS pipeline -------
__global__ __launch_bounds__(256) void attn_kernel(
    const unsigned short* __restrict__ qb, const unsigned short* __restrict__ kb,
    const unsigned short* __restrict__ vt, unsigned short* __restrict__ pO,
    float* __restrict__ pS) {
  __shared__ alignas(16) unsigned short lK[2][64 * 64];
  __shared__ alignas(16) unsigned short lV[2][64 * 64];
  int tid = threadIdx.x;
  int wid = tid >> 6, lane = tid & 63;
  int g = lane >> 4, lr = lane & 15;
  int f = blockIdx.x;                  // 0..1023
  int xcd = f & 7, rest = f >> 3;
  int bh = xcd + 8 * (rest & 3);       // 4 bh per XCD -> K/V L2-resident
  int qt = (rest >> 2) & 15;           // 128-row q-tile
  int s  = (rest >> 6) & 1;            // KV half
  const size_t koff = (size_t)bh * T_DIM * HD_DIM;
  const size_t voff = (size_t)bh * HD_DIM * T_DIM;

  int srow = tid >> 3;
  int gch  = (tid & 7) ^ (srow & 7);
  const unsigned short* ks0 = kb + koff +
      ((size_t)(s * 1024) + srow) * HD_DIM + gch * 8;
  const unsigned short* vs0 = vt + voff +
      (size_t)srow * T_DIM + s * 1024 + gch * 8;

#define STAGE_TILE(buf, kofs, vofs)                                            \
  do {                                                                         \
    gload_lds16(ks0 + (kofs),                 lK[buf] + wid * 512);            \
    gload_lds16(ks0 + (kofs) + 32 * HD_DIM,   lK[buf] + 2048 + wid * 512);     \
    gload_lds16(vs0 + (vofs),                 lV[buf] + wid * 512);            \
    gload_lds16(vs0 + (vofs) + (size_t)32 * T_DIM, lV[buf] + 2048 + wid * 512);\
  } while (0)

  bf16x8 qf[2][2];
  {
    const float QS = 0.125f * 1.44269504f;
#pragma unroll
    for (int qa = 0; qa < 2; ++qa) {
      int qrow = qt * 128 + wid * 32 + qa * 16 + lr;
#pragma unroll
      for (int ks = 0; ks < 2; ++ks) {
        bf16x8 raw = *(const bf16x8*)(qb + koff + (size_t)qrow * HD_DIM + ks * 32 + g * 8);
#pragma unroll
        for (int j = 0; j < 8; ++j) qf[qa][ks][j] = (__bf16)((float)raw[j] * QS);
      }
    }
  }

  bf16x8 onesf;
#pragma unroll
  for (int j = 0; j < 8; ++j) onesf[j] = (__bf16)1.0f;

  f32x4 accO[2][4] = {};
  f32x4 accS[2] = {};

  STAGE_TILE(0, 0, 0);

#define PROCESS(BUF, TT, LAST)                                                 \
  do {                                                                         \
    __builtin_amdgcn_s_barrier();                                              \
    if (!(LAST)) {                                                             \
      size_t s1 = (size_t)((TT) + 1) * 64;                                     \
      STAGE_TILE((BUF) ^ 1, s1 * HD_DIM, s1);                                  \
      asm volatile("s_waitcnt vmcnt(4)" ::: "memory");                         \
    } else {                                                                   \
      asm volatile("s_waitcnt vmcnt(0)" ::: "memory");                         \
    }                                                                          \
    __builtin_amdgcn_s_barrier();                                              \
    __builtin_amdgcn_sched_barrier(0);                                         \
    const unsigned short* Kc = lK[BUF];                                        \
    const unsigned short* Vc = lV[BUF];                                        \
    f32x4 s4[2][4];                                                            \
    __builtin_amdgcn_s_setprio(1);                                             \
    _Pragma("unroll")                                                          \
    for (int cf = 0; cf < 4; ++cf) {                                           \
      int row = cf * 16 + lr;                                                  \
      int sw = (row & 7) << 3;                                                 \
      bf16x8 k0 = *(const bf16x8*)(Kc + row * 64 + ((g * 8) ^ sw));            \
      bf16x8 k1 = *(const bf16x8*)(Kc + row * 64 + ((32 + g * 8) ^ sw));       \
      _Pragma("unroll")                                                        \
      for (int qa = 0; qa < 2; ++qa) {                                         \
        f32x4 s = {-8.0f, -8.0f, -8.0f, -8.0f};                                \
        s = __builtin_amdgcn_mfma_f32_16x16x32_bf16(k0, qf[qa][0], s, 0, 0, 0);\
        s = __builtin_amdgcn_mfma_f32_16x16x32_bf16(k1, qf[qa][1], s, 0, 0, 0);\
        s4[qa][cf] = s;                                                        \
      }                                                                        \
    }                                                                          \
    __builtin_amdgcn_s_setprio(0);                                             \
    bf16x8 pf[2][2];                                                           \
    _Pragma("unroll")                                                          \
    for (int qa = 0; qa < 2; ++qa)                                             \
      _Pragma("unroll")                                                        \
      for (int j = 0; j < 8; ++j) {                                            \
        pf[qa][0][j] = (__bf16)__builtin_amdgcn_exp2f(s4[qa][(j >> 2)][j & 3]);\
        pf[qa][1][j] = (__bf16)__builtin_amdgcn_exp2f(s4[qa][2 + (j >> 2)][j & 3]);\
      }                                                                        \
    __builtin_amdgcn_s_setprio(1);                                             \
    _Pragma("unroll")                                                          \
    for (int ks = 0; ks < 2; ++ks) {                                           \
      _Pragma("unroll")                                                        \
      for (int qa = 0; qa < 2; ++qa)                                           \
        accS[qa] = __builtin_amdgcn_mfma_f32_16x16x32_bf16(onesf, pf[qa][ks], accS[qa], 0, 0, 0); \
      _Pragma("unroll")                                                        \
      for (int df = 0; df < 4; ++df) {                                         \
        int row = df * 16 + lr;                                                \
        int sw = (row & 7) << 3;                                               \
        bf16x8 vf = *(const bf16x8*)(Vc + row * 64 + ((ks * 32 + g * 8) ^ sw));\
        _Pragma("unroll")                                                      \
        for (int qa = 0; qa < 2; ++qa)                                         \
          accO[qa][df] = __builtin_amdgcn_mfma_f32_16x16x32_bf16(vf, pf[qa][ks], accO[qa][df], 0, 0, 0); \
      }                                                                        \
    }                                                                          \
    __builtin_amdgcn_s_setprio(0);                                             \
  } while (0)

  for (int t2 = 0; t2 < 16; t2 += 2) {
    PROCESS(0, t2, false);
    PROCESS(1, t2 + 1, t2 + 1 == 15);
  }
#undef PROCESS
#undef STAGE_TILE

  unsigned short* pOb = pO + (size_t)((s * 32 + bh) * 16 + qt) * (64 * 128);
#pragma unroll
  for (int qa = 0; qa < 2; ++qa)
#pragma unroll
    for (int df = 0; df < 4; ++df)
#pragma unroll
      for (int r = 0; r < 4; ++r)
        pOb[(df * 16 + g * 4 + r) * 128 + wid * 32 + qa * 16 + lr] =
            f2bf(accO[qa][df][r]);
  if (g == 0) {
    float* pSb = pS + (size_t)((s * 32 + bh) * 16 + qt) * 128;
#pragma unroll
    for (int qa = 0; qa < 2; ++qa)
      pSb[wid * 32 + qa * 16 + lr] = accS[qa][0];
  }
}

// ---------------- combine partials: ctx = (O0+O1)/(S0+S1), transpose ------
__global__ __launch_bounds__(256) void reduce_kernel(
    const unsigned short* __restrict__ pO, const float* __restrict__ pS,
    unsigned short* __restrict__ ctx) {
  __shared__ float lo[64][65];
  __shared__ float ls[64];
  int tid = threadIdx.x;
  int bq = blockIdx.x;               // 0..1023
  int bh = bq & 31, qt2 = bq >> 5;   // qt2: 64-row group 0..31
  int b = bh >> 4, h = bh & 15;
  int qt = qt2 >> 1, half = qt2 & 1;
  size_t base0 = (size_t)((0 * 32 + bh) * 16 + qt) * 8192 + half * 64;
  size_t base1 = (size_t)((1 * 32 + bh) * 16 + qt) * 8192 + half * 64;
  int d = tid >> 2, c = (tid & 3) * 16;
  u16x8 a0 = *(const u16x8*)(pO + base0 + d * 128 + c);
  u16x8 a1 = *(const u16x8*)(pO + base0 + d * 128 + c + 8);
  u16x8 b0 = *(const u16x8*)(pO + base1 + d * 128 + c);
  u16x8 b1 = *(const u16x8*)(pO + base1 + d * 128 + c + 8);
#pragma unroll
  for (int j = 0; j < 8; ++j) {
    lo[d][c + j]     = bf2f(a0[j]) + bf2f(b0[j]);
    lo[d][c + 8 + j] = bf2f(a1[j]) + bf2f(b1[j]);
  }
  if (tid < 64)
    ls[tid] = pS[(size_t)((0 * 32 + bh) * 16 + qt) * 128 + half * 64 + tid] +
              pS[(size_t)((1 * 32 + bh) * 16 + qt) * 128 + half * 64 + tid];
  __syncthreads();
  int q = tid >> 2, dc = tid & 3;
  float inv = 1.0f / ls[q];
  u16x8 o0, o1;
#pragma unroll
  for (int k = 0; k < 8; ++k) {
    o0[k] = f2bf(lo[dc * 16 + k][q] * inv);
    o1[k] = f2bf(lo[dc * 16 + 8 + k][q] * inv);
  }
  size_t row = ((size_t)(qt2 * 64 + q) * B_DIM + b) * E_DIM + h * HD_DIM + dc * 16;
  *(u16x8*)(ctx + row)     = o0;
  *(u16x8*)(ctx + row + 8) = o1;
}

// ---------------- launcher ----------------
extern "C" void kernel_launch(void* const* d_in, const int* in_sizes, int n_in,
                              void* d_out, int out_size, void* d_ws, size_t ws_size,
                              hipStream_t stream) {
  const float* query = (const float*)d_in[0];
  const float* gamma = (const float*)d_in[1];
  const float* beta  = (const float*)d_in[2];
  const float* w_in  = (const float*)d_in[3];
  const float* w_out = (const float*)d_in[4];
  float* out = (float*)d_out;

  unsigned short* ws    = (unsigned short*)d_ws;
  unsigned short* ln    = ws;                                  // 8 MB
  unsigned short* winb  = ln    + (size_t)M_DIM * E_DIM;       // 6 MB
  unsigned short* woutb = winb  + (size_t)3 * E_DIM * E_DIM;   // 2 MB
  unsigned short* qkv   = woutb + (size_t)E_DIM * E_DIM;       // 24 MB
  unsigned short* qbuf  = qkv;
  unsigned short* kbuf  = qkv + (size_t)BH_DIM * T_DIM * HD_DIM;
  unsigned short* vbuf  = kbuf + (size_t)BH_DIM * T_DIM * HD_DIM;
  unsigned short* pO    = vbuf + (size_t)BH_DIM * T_DIM * HD_DIM; // 16 MB
  float*          pS    = (float*)(pO + (size_t)2 * BH_DIM * 16 * 64 * 128); // 0.5 MB
  unsigned short* vtb   = ln;    // reuse: ln consumed by gemm0 before transpose
  unsigned short* ctx   = vbuf;  // reuse: vbuf consumed by transpose before reduce

  prep_kernel<<<dim3(M_DIM + 4096), dim3(256), 0, stream>>>(
      query, gamma, beta, ln,
      w_in, winb, 3 * E_DIM * E_DIM / 4, w_out, woutb, E_DIM * E_DIM / 4);
  gemm0_kernel<<<dim3(3 * E_DIM / 128, M_DIM / 128), dim3(256), 0, stream>>>(
      ln, winb, qkv);
  transpose_v_kernel<<<dim3(T_DIM / 64, BH_DIM), dim3(256), 0, stream>>>(vbuf, vtb);
  attn_kernel<<<dim3(1024), dim3(256), 0, stream>>>(qbuf, kbuf, vtb, pO, pS);
  reduce_kernel<<<dim3(1024), dim3(256), 0, stream>>>(pO, pS, ctx);
  gemm1_kernel<<<dim3(E_DIM / 64, M_DIM / 128), dim3(256), 0, stream>>>(
      ctx, woutb, query, out);
}

// Round 14
// 121.924 us; speedup vs baseline: 1.2238x; 1.0674x over previous
//
#include <hip/hip_runtime.h>
#include <hip/hip_bf16.h>
#include <math.h>

#define T_DIM 2048
#define B_DIM 2
#define E_DIM 1024
#define H_DIM 16
#define HD_DIM 64
#define M_DIM (T_DIM * B_DIM)   // 4096 rows (t*B+b)
#define BH_DIM (B_DIM * H_DIM)  // 32 head-batches

using bf16x8 = __attribute__((ext_vector_type(8))) __bf16;
using u16x8  = __attribute__((ext_vector_type(8))) unsigned short;
using f32x4  = __attribute__((ext_vector_type(4))) float;

static __device__ __forceinline__ unsigned short f2bf(float f) {
  unsigned u = __builtin_bit_cast(unsigned, f);
  u += 0x7fff + ((u >> 16) & 1);   // RNE
  return (unsigned short)(u >> 16);
}

__device__ __forceinline__ void gload_lds16(const void* g, void* l) {
  __builtin_amdgcn_global_load_lds(
      (const __attribute__((address_space(1))) unsigned int*)g,
      (__attribute__((address_space(3))) unsigned int*)l, 16, 0, 0);
}

// ---------------- prep: LN rows (blocks 0..4095) + weight casts (4096..8191)
__global__ __launch_bounds__(256) void prep_kernel(
    const float* __restrict__ q, const float* __restrict__ gamma,
    const float* __restrict__ beta, unsigned short* __restrict__ ln_out,
    const float* __restrict__ w1, unsigned short* __restrict__ o1, int n1,
    const float* __restrict__ w2, unsigned short* __restrict__ o2, int n2) {
  int blk = blockIdx.x;
  int tid = threadIdx.x;
  if (blk >= M_DIM) {
    int i = (blk - M_DIM) * 256 + tid;
    const float* in; unsigned short* out; int idx;
    if (i < n1) { in = w1; out = o1; idx = i; }
    else if (i < n1 + n2) { in = w2; out = o2; idx = i - n1; }
    else return;
    float4 v = ((const float4*)in)[idx];
    ushort4 o;
    o.x = f2bf(v.x); o.y = f2bf(v.y); o.z = f2bf(v.z); o.w = f2bf(v.w);
    ((ushort4*)out)[idx] = o;
    return;
  }
  int row = blk;
  const float4* qr = (const float4*)(q + (size_t)row * E_DIM);
  float4 x = qr[tid];
  float s  = x.x + x.y + x.z + x.w;
  float ss = x.x * x.x + x.y * x.y + x.z * x.z + x.w * x.w;
#pragma unroll
  for (int off = 32; off >= 1; off >>= 1) {
    s  += __shfl_xor(s, off, 64);
    ss += __shfl_xor(ss, off, 64);
  }
  __shared__ float red[8];
  int wid = tid >> 6, lane = tid & 63;
  if (lane == 0) { red[wid] = s; red[4 + wid] = ss; }
  __syncthreads();
  s  = red[0] + red[1] + red[2] + red[3];
  ss = red[4] + red[5] + red[6] + red[7];
  float mean = s * (1.0f / E_DIM);
  float var  = ss * (1.0f / E_DIM) - mean * mean;
  float rstd = rsqrtf(var + 1e-5f);
  float4 g4 = ((const float4*)gamma)[tid];
  float4 b4 = ((const float4*)beta)[tid];
  ushort4 o;
  o.x = f2bf((x.x - mean) * rstd * g4.x + b4.x);
  o.y = f2bf((x.y - mean) * rstd * g4.y + b4.y);
  o.z = f2bf((x.z - mean) * rstd * g4.z + b4.z);
  o.w = f2bf((x.w - mean) * rstd * g4.w + b4.w);
  ((ushort4*)(ln_out + (size_t)row * E_DIM))[tid] = o;
}

// ---------------- GEMM0: qkv = ln @ Win^T, scatter to [3][bh][t][64] ------
__global__ __launch_bounds__(256) void gemm0_kernel(
    const unsigned short* __restrict__ A, const unsigned short* __restrict__ Bw,
    unsigned short* __restrict__ out_qkv) {
  __shared__ alignas(16) unsigned short lA[128 * 32];
  __shared__ alignas(16) unsigned short lB[128 * 32];
  int tid = threadIdx.x;
  int wid = tid >> 6, lane = tid & 63;
  int wm = wid >> 1, wn = wid & 1;
  int g = lane >> 4, lr = lane & 15;
  int m0 = blockIdx.y * 128, n0 = blockIdx.x * 128;
  f32x4 acc[4][4] = {};

  for (int k0 = 0; k0 < E_DIM; k0 += 32) {
#pragma unroll
    for (int c = 0; c < 2; ++c) {
      int f16 = c * 256 + tid;
      int row = f16 >> 2, col8 = (f16 & 3) << 3;
      gload_lds16(A  + (size_t)(m0 + row) * E_DIM + k0 + col8,
                  lA + (size_t)(c * 256 + wid * 64) * 8);
      gload_lds16(Bw + (size_t)(n0 + row) * E_DIM + k0 + col8,
                  lB + (size_t)(c * 256 + wid * 64) * 8);
    }
    __syncthreads();
    bf16x8 af[4], bfr[4];
#pragma unroll
    for (int r = 0; r < 4; ++r) {
      af[r]  = *(const bf16x8*)(lA + (wm * 64 + r * 16 + lr) * 32 + g * 8);
      bfr[r] = *(const bf16x8*)(lB + (wn * 64 + r * 16 + lr) * 32 + g * 8);
    }
#pragma unroll
    for (int mr = 0; mr < 4; ++mr)
#pragma unroll
      for (int nr = 0; nr < 4; ++nr)
        acc[mr][nr] = __builtin_amdgcn_mfma_f32_16x16x32_bf16(
            af[mr], bfr[nr], acc[mr][nr], 0, 0, 0);
    __syncthreads();
  }

#pragma unroll
  for (int mr = 0; mr < 4; ++mr) {
#pragma unroll
    for (int nr = 0; nr < 4; ++nr) {
#pragma unroll
      for (int r = 0; r < 4; ++r) {
        int grow = m0 + wm * 64 + mr * 16 + g * 4 + r;
        int gcol = n0 + wn * 64 + nr * 16 + lr;
        int which = gcol >> 10, rem = gcol & 1023;
        int h = rem >> 6, d = rem & 63;
        int t = grow >> 1, b = grow & 1;
        out_qkv[(size_t)which * (BH_DIM * T_DIM * HD_DIM) +
                ((size_t)(b * H_DIM + h) * T_DIM + t) * HD_DIM + d] =
            f2bf(acc[mr][nr][r]);
      }
    }
  }
}

// ---------------- GEMM1: out = resid + ctx @ Wout^T (128x64 tile) --------
__global__ __launch_bounds__(256) void gemm1_kernel(
    const unsigned short* __restrict__ A, const unsigned short* __restrict__ Bw,
    const float* __restrict__ resid, float* __restrict__ out) {
  __shared__ alignas(16) unsigned short lA[128 * 32];
  __shared__ alignas(16) unsigned short lB[64 * 32];
  int tid = threadIdx.x;
  int wid = tid >> 6, lane = tid & 63;
  int g = lane >> 4, lr = lane & 15;
  int m0 = blockIdx.y * 128, n0 = blockIdx.x * 64;
  f32x4 acc[2][4] = {};

  for (int k0 = 0; k0 < E_DIM; k0 += 32) {
#pragma unroll
    for (int c = 0; c < 2; ++c) {
      int f16 = c * 256 + tid;
      int row = f16 >> 2, col8 = (f16 & 3) << 3;
      gload_lds16(A + (size_t)(m0 + row) * E_DIM + k0 + col8,
                  lA + (size_t)(c * 256 + wid * 64) * 8);
    }
    {
      int row = tid >> 2, col8 = (tid & 3) << 3;
      gload_lds16(Bw + (size_t)(n0 + row) * E_DIM + k0 + col8,
                  lB + (size_t)(wid * 64) * 8);
    }
    __syncthreads();
    bf16x8 af[2], bfr[4];
#pragma unroll
    for (int r = 0; r < 2; ++r)
      af[r] = *(const bf16x8*)(lA + (wid * 32 + r * 16 + lr) * 32 + g * 8);
#pragma unroll
    for (int r = 0; r < 4; ++r)
      bfr[r] = *(const bf16x8*)(lB + (r * 16 + lr) * 32 + g * 8);
#pragma unroll
    for (int mr = 0; mr < 2; ++mr)
#pragma unroll
      for (int nr = 0; nr < 4; ++nr)
        acc[mr][nr] = __builtin_amdgcn_mfma_f32_16x16x32_bf16(
            af[mr], bfr[nr], acc[mr][nr], 0, 0, 0);
    __syncthreads();
  }

#pragma unroll
  for (int mr = 0; mr < 2; ++mr) {
#pragma unroll
    for (int nr = 0; nr < 4; ++nr) {
#pragma unroll
      for (int r = 0; r < 4; ++r) {
        int grow = m0 + wid * 32 + mr * 16 + g * 4 + r;
        int gcol = n0 + nr * 16 + lr;
        size_t idx = (size_t)grow * E_DIM + gcol;
        out[idx] = resid[idx] + acc[mr][nr][r];
      }
    }
  }
}

// ---------------- V transpose: [bh][t][d] -> [bh][d][perm(t)] -------------
// Column p holds logical key tl(p) = (ks*2+(j>>2))*16+g*4+(j&3), ks=p>>5,
// g=(p>>3)&3, j=p&7 — matches attn's register-P layout after swapped QK^T.
__global__ __launch_bounds__(256) void transpose_v_kernel(
    const unsigned short* __restrict__ vb, unsigned short* __restrict__ vt) {
  __shared__ alignas(16) unsigned short tl[64 * 72];
  int tid = threadIdx.x;
  int bh = blockIdx.y, t0 = blockIdx.x * 64;
  const unsigned short* src = vb + ((size_t)bh * T_DIM + t0) * HD_DIM;
#pragma unroll
  for (int e = 0; e < 2; ++e) {
    int i8 = e * 256 + tid;
    int r = i8 >> 3;
    int c = (i8 & 7) * 8;
    int hsh = (r ^ (r >> 3)) & 7;
    bf16x8 v = *(const bf16x8*)(src + (size_t)r * HD_DIM + c);
    *(bf16x8*)(tl + r * 72 + (c ^ (hsh << 3))) = v;
  }
  __syncthreads();
  unsigned short* dst = vt + (size_t)bh * HD_DIM * T_DIM + t0;
#pragma unroll
  for (int e = 0; e < 2; ++e) {
    int i8 = e * 256 + tid;
    int d = i8 >> 3;
    int tc = (i8 & 7) * 8;
    u16x8 o;
#pragma unroll
    for (int j = 0; j < 8; ++j) {
      int p = tc + j;
      int ks = p >> 5, gg = (p >> 3) & 3, jl = p & 7;
      int r = (ks * 2 + (jl >> 2)) * 16 + gg * 4 + (jl & 3);
      int hsh = (r ^ (r >> 3)) & 7;
      o[j] = tl[r * 72 + (d ^ (hsh << 3))];
    }
    *(u16x8*)(dst + (size_t)d * T_DIM + tc) = o;
  }
}

// ---------------- Flash attention v8: r11 + intra-wave software pipeline --
// 3-buffer LDS, ONE barrier/tile. At iter t: stage(t+2); QK(t+1) MFMAs
// INTERLEAVE with exp2(t) VALU (independent); then PV(t). Swapped QK^T ->
// register-resident P; fixed-max softmax P=2^(s-8); rowsum via mfma(ones,P).
// Safety: barrier(t) => all waves finished PV(t-1) (buf(t-1) dead before
// stage) and all waves' stage(t+1) landed (own vmcnt(0) precedes barrier).
__global__ __launch_bounds__(256) void attn_kernel(
    const unsigned short* __restrict__ qb, const unsigned short* __restrict__ kb,
    const unsigned short* __restrict__ vt, unsigned short* __restrict__ ctx) {
  __shared__ alignas(16) unsigned short lK[3][64 * 64];
  __shared__ alignas(16) unsigned short lV[3][64 * 64];
  int tid = threadIdx.x;
  int wid = tid >> 6, lane = tid & 63;
  int g = lane >> 4, lr = lane & 15;
  int f = blockIdx.x;                  // 0..511
  int xcd = f & 7, rest = f >> 3;
  int bh = xcd + 8 * (rest & 3);       // 4 bh per XCD -> K/V L2-resident
  int qt = rest >> 2;                  // 0..15 (128-row q-tiles)
  int b = bh >> 4, h = bh & 15;
  const size_t koff = (size_t)bh * T_DIM * HD_DIM;
  const size_t voff = (size_t)bh * HD_DIM * T_DIM;

  int srow = tid >> 3;
  int gch  = (tid & 7) ^ (srow & 7);
  const unsigned short* ks0 = kb + koff + (size_t)srow * HD_DIM + gch * 8;
  const unsigned short* vs0 = vt + voff + (size_t)srow * T_DIM + gch * 8;

#define STAGE_TILE(buf, kofs, vofs)                                            \
  do {                                                                         \
    gload_lds16(ks0 + (kofs),                 lK[buf] + wid * 512);            \
    gload_lds16(ks0 + (kofs) + 32 * HD_DIM,   lK[buf] + 2048 + wid * 512);     \
    gload_lds16(vs0 + (vofs),                 lV[buf] + wid * 512);            \
    gload_lds16(vs0 + (vofs) + (size_t)32 * T_DIM, lV[buf] + 2048 + wid * 512);\
  } while (0)

  // Q fragments, scale 1/8 * log2(e) folded in
  bf16x8 qf[2][2];
  {
    const float QS = 0.125f * 1.44269504f;
#pragma unroll
    for (int qa = 0; qa < 2; ++qa) {
      int qrow = qt * 128 + wid * 32 + qa * 16 + lr;
#pragma unroll
      for (int ks = 0; ks < 2; ++ks) {
        bf16x8 raw = *(const bf16x8*)(qb + koff + (size_t)qrow * HD_DIM + ks * 32 + g * 8);
#pragma unroll
        for (int j = 0; j < 8; ++j) qf[qa][ks][j] = (__bf16)((float)raw[j] * QS);
      }
    }
  }

  bf16x8 onesf;
#pragma unroll
  for (int j = 0; j < 8; ++j) onesf[j] = (__bf16)1.0f;

  f32x4 accO[2][4] = {};   // accO[qa][df]: O^T[d=df*16+g*4+r][q=lr]
  f32x4 accS[2] = {};
  f32x4 s4c[2][4];         // carried QK(t) scores (log2 domain)

#define QK_TILE(BUF, S4)                                                       \
  do {                                                                         \
    const unsigned short* Kc = lK[BUF];                                        \
    _Pragma("unroll")                                                          \
    for (int cf = 0; cf < 4; ++cf) {                                           \
      int row = cf * 16 + lr;                                                  \
      int sw = (row & 7) << 3;                                                 \
      bf16x8 k0 = *(const bf16x8*)(Kc + row * 64 + ((g * 8) ^ sw));            \
      bf16x8 k1 = *(const bf16x8*)(Kc + row * 64 + ((32 + g * 8) ^ sw));       \
      _Pragma("unroll")                                                        \
      for (int qa = 0; qa < 2; ++qa) {                                         \
        f32x4 s = {-8.0f, -8.0f, -8.0f, -8.0f};                                \
        s = __builtin_amdgcn_mfma_f32_16x16x32_bf16(k0, qf[qa][0], s, 0, 0, 0);\
        s = __builtin_amdgcn_mfma_f32_16x16x32_bf16(k1, qf[qa][1], s, 0, 0, 0);\
        S4[qa][cf] = s;                                                        \
      }                                                                        \
    }                                                                          \
  } while (0)

  // prologue: stage tiles 0,1; QK(0)
  STAGE_TILE(0, 0, 0);
  STAGE_TILE(1, (size_t)64 * HD_DIM, 64);
  asm volatile("s_waitcnt vmcnt(4)" ::: "memory");
  __builtin_amdgcn_s_barrier();
  __builtin_amdgcn_sched_barrier(0);
  QK_TILE(0, s4c);

#define PROCESS(B0, B1, B2, TT, STG, QKN)                                      \
  do {                                                                         \
    asm volatile("s_waitcnt vmcnt(0)" ::: "memory");                           \
    __builtin_amdgcn_s_barrier();                                              \
    __builtin_amdgcn_sched_barrier(0);                                         \
    if (STG) {                                                                 \
      size_t s2 = (size_t)((TT) + 2) * 64;                                     \
      STAGE_TILE(B2, s2 * HD_DIM, s2);                                         \
    }                                                                          \
    __builtin_amdgcn_s_setprio(1);                                             \
    f32x4 s4n[2][4];                                                           \
    if (QKN) QK_TILE(B1, s4n);                                                 \
    bf16x8 pf[2][2];                                                           \
    _Pragma("unroll")                                                          \
    for (int qa = 0; qa < 2; ++qa)                                             \
      _Pragma("unroll")                                                        \
      for (int j = 0; j < 8; ++j) {                                            \
        pf[qa][0][j] = (__bf16)__builtin_amdgcn_exp2f(s4c[qa][(j >> 2)][j & 3]);\
        pf[qa][1][j] = (__bf16)__builtin_amdgcn_exp2f(s4c[qa][2 + (j >> 2)][j & 3]);\
      }                                                                        \
    {                                                                          \
      const unsigned short* Vc = lV[B0];                                       \
      _Pragma("unroll")                                                        \
      for (int ks = 0; ks < 2; ++ks) {                                         \
        _Pragma("unroll")                                                      \
        for (int qa = 0; qa < 2; ++qa)                                         \
          accS[qa] = __builtin_amdgcn_mfma_f32_16x16x32_bf16(onesf, pf[qa][ks], accS[qa], 0, 0, 0); \
        _Pragma("unroll")                                                      \
        for (int df = 0; df < 4; ++df) {                                       \
          int row = df * 16 + lr;                                              \
          int sw = (row & 7) << 3;                                             \
          bf16x8 vf = *(const bf16x8*)(Vc + row * 64 + ((ks * 32 + g * 8) ^ sw));\
          _Pragma("unroll")                                                    \
          for (int qa = 0; qa < 2; ++qa)                                       \
            accO[qa][df] = __builtin_amdgcn_mfma_f32_16x16x32_bf16(vf, pf[qa][ks], accO[qa][df], 0, 0, 0); \
        }                                                                      \
      }                                                                        \
    }                                                                          \
    __builtin_amdgcn_s_setprio(0);                                             \
    if (QKN) {                                                                 \
      _Pragma("unroll")                                                        \
      for (int qa = 0; qa < 2; ++qa)                                           \
        _Pragma("unroll")                                                      \
        for (int cf = 0; cf < 4; ++cf)                                         \
          s4c[qa][cf] = s4n[qa][cf];                                           \
    }                                                                          \
  } while (0)

  for (int t3 = 0; t3 < 30; t3 += 3) {
    PROCESS(0, 1, 2, t3 + 0, true, true);
    PROCESS(1, 2, 0, t3 + 1, true, true);
    PROCESS(2, 0, 1, t3 + 2, true, true);
  }
  PROCESS(0, 1, 2, 30, false, true);   // QK(31), no stage
  PROCESS(1, 2, 0, 31, false, false);  // drain: exp2+PV(31) only
#undef PROCESS
#undef QK_TILE
#undef STAGE_TILE

  // Epilogue: O^T regs -> LDS (stride 72, reuse lK) -> coalesced ctx stores
  __syncthreads();
  unsigned short* sc = (unsigned short*)lK + wid * (32 * 72);
  float invl[2];
  invl[0] = 1.0f / accS[0][0];
  invl[1] = 1.0f / accS[1][0];
#pragma unroll
  for (int qa = 0; qa < 2; ++qa)
#pragma unroll
    for (int df = 0; df < 4; ++df)
#pragma unroll
      for (int r = 0; r < 4; ++r)
        sc[(qa * 16 + lr) * 72 + df * 16 + g * 4 + r] =
            f2bf(accO[qa][df][r] * invl[qa]);
  __syncthreads();
#pragma unroll
  for (int i = 0; i < 4; ++i) {
    int idx = i * 64 + lane;
    int row = idx >> 3, ch = idx & 7;
    u16x8 v8 = *(const u16x8*)(sc + row * 72 + ch * 8);
    int t = qt * 128 + wid * 32 + row;
    *(u16x8*)(&ctx[((size_t)t * B_DIM + b) * E_DIM + h * HD_DIM + ch * 8]) = v8;
  }
}

// ---------------- launcher ----------------
extern "C" void kernel_launch(void* const* d_in, const int* in_sizes, int n_in,
                              void* d_out, int out_size, void* d_ws, size_t ws_size,
                              hipStream_t stream) {
  const float* query = (const float*)d_in[0];
  const float* gamma = (const float*)d_in[1];
  const float* beta  = (const float*)d_in[2];
  const float* w_in  = (const float*)d_in[3];
  const float* w_out = (const float*)d_in[4];
  float* out = (float*)d_out;

  unsigned short* ws    = (unsigned short*)d_ws;
  unsigned short* ln    = ws;                                 // 8 MB
  unsigned short* winb  = ln + (size_t)M_DIM * E_DIM;         // 6 MB
  unsigned short* woutb = winb + (size_t)3 * E_DIM * E_DIM;   // 2 MB
  unsigned short* qkv   = woutb + (size_t)E_DIM * E_DIM;      // 24 MB

  unsigned short* qbuf = qkv;
  unsigned short* kbuf = qkv + (size_t)BH_DIM * T_DIM * HD_DIM;
  unsigned short* vbuf = kbuf + (size_t)BH_DIM * T_DIM * HD_DIM;
  unsigned short* vtb  = ln;    // reuse: ln consumed by gemm0 before transpose
  unsigned short* ctx  = vbuf;  // reuse: vbuf consumed by transpose before attn

  prep_kernel<<<dim3(M_DIM + 4096), dim3(256), 0, stream>>>(
      query, gamma, beta, ln,
      w_in, winb, 3 * E_DIM * E_DIM / 4, w_out, woutb, E_DIM * E_DIM / 4);
  gemm0_kernel<<<dim3(3 * E_DIM / 128, M_DIM / 128), dim3(256), 0, stream>>>(
      ln, winb, qkv);
  transpose_v_kernel<<<dim3(T_DIM / 64, BH_DIM), dim3(256), 0, stream>>>(vbuf, vtb);
  attn_kernel<<<dim3(512), dim3(256), 0, stream>>>(qbuf, kbuf, vtb, ctx);
  gemm1_kernel<<<dim3(E_DIM / 64, M_DIM / 128), dim3(256), 0, stream>>>(
      ctx, woutb, query, out);
}